// Round 6
// baseline (38.066 us; speedup 1.0000x reference)
//
#include <hip/hip_runtime.h>

#define NCLS 19
#define BINS 51
#define NPIX 4096
#define NFEAT 256
#define CHUNKS 64
#define TILE 1024
#define TWO_PI_F 6.2831853071795864769f
#define LOG2E_F 1.4426950408889634f
#define EXP2F(v) __builtin_amdgcn_exp2f(v)

// ws layout: float partial[NFEAT*18] @ 0 (18432B); int base_g[32] @ 18944; int idx_g[NPIX] @ 19072

// ---- kernel 0: global deterministic class bucketing (labels only) ----
__global__ __launch_bounds__(1024)
void bucket_k(const int* __restrict__ lab, int* __restrict__ base_g,
              int* __restrict__ idx_g) {
    __shared__ int cnt[CHUNKS][NCLS];
    __shared__ int base_s[NCLS + 1];
    __shared__ int tot_s[NCLS];
    const int tid = threadIdx.x, lane = tid & 63, wave = tid >> 6;  // 16 waves

    // per-chunk per-class counts via ballot
    #pragma unroll
    for (int k = 0; k < 4; ++k) {
        int ch = wave + 16 * k;
        int v  = lab[ch * 64 + lane];
        for (int c = 1; c < NCLS; ++c) {
            unsigned long long m = __ballot(v == c);
            if (lane == 0) cnt[ch][c] = (int)__popcll(m);
        }
    }
    __syncthreads();

    // per-class exclusive scan over 64 chunks (lane = chunk)
    for (int c = wave + 1; c < NCLS; c += 16) {
        int v = cnt[lane][c], s = v;
        #pragma unroll
        for (int off = 1; off < 64; off <<= 1) {
            int t = __shfl_up(s, off, 64);
            if (lane >= off) s += t;
        }
        cnt[lane][c] = s - v;
        if (lane == 63) tot_s[c] = s;
    }
    __syncthreads();
    if (tid == 0) {
        int run = 0;
        base_s[0] = 0;
        for (int c = 1; c < NCLS; ++c) { base_s[c] = run; run += tot_s[c]; }
        base_s[NCLS] = run;
        for (int c = 0; c <= NCLS; ++c) base_g[c] = base_s[c];
    }
    __syncthreads();

    // rank-based scatter of pixel indices (deterministic order)
    #pragma unroll
    for (int k = 0; k < 4; ++k) {
        int ch = wave + 16 * k;
        int p  = ch * 64 + lane;
        int v  = lab[p];
        for (int c = 1; c < NCLS; ++c) {
            unsigned long long m = __ballot(v == c);
            if (v == c) {
                int rank = (int)__popcll(m & ((1ull << lane) - 1ull));
                idx_g[base_s[c] + cnt[ch][c] + rank] = p;
            }
        }
    }
}

// ---- kernel 1: per-(feature,class) stats + KDE + smooth-L1 ----
__global__ __launch_bounds__(256)
void hist_main(const float* __restrict__ x, const int* __restrict__ base_g,
               const int* __restrict__ idx_g, float* __restrict__ partial) {
    const int f   = blockIdx.x;
    const int cm1 = blockIdx.y;        // 0..17
    const int c   = cm1 + 1;
    const int tid = threadIdx.x, lane = tid & 63, wave = tid >> 6;

    __shared__ __align__(16) float xs[TILE + 4];
    __shared__ float s_red[8];
    __shared__ float s_acc[4][64];

    const int st = base_g[c];
    const int n  = base_g[c + 1] - st;
    if (n == 0) { if (tid == 0) partial[cm1 * NFEAT + f] = 0.f; return; }

    // gather + stats (stage first tile into LDS on the fly)
    const float* xrow = x + (size_t)f * NPIX;
    float s1 = 0.f, s2 = 0.f;
    for (int i = tid; i < n; i += 256) {
        float v = xrow[idx_g[st + i]];
        if (i < TILE) xs[i] = v;
        s1 += v; s2 += v * v;
    }
    #pragma unroll
    for (int off = 32; off; off >>= 1) {
        s1 += __shfl_xor(s1, off, 64);
        s2 += __shfl_xor(s2, off, 64);
    }
    if (lane == 0) { s_red[wave] = s1; s_red[4 + wave] = s2; }

    const int nt0  = (n < TILE) ? n : TILE;
    const int N4t0 = (nt0 + 3) & ~3;
    if (tid < N4t0 - nt0) xs[nt0 + tid] = 1e19f;   // sentinel pad: exp2 -> 0
    __syncthreads();

    const float sum1 = s_red[0] + s_red[1] + s_red[2] + s_red[3];
    const float sum2 = s_red[4] + s_red[5] + s_red[6] + s_red[7];
    const float fn   = (float)n;
    const float miu  = sum1 / fn;
    const float var  = fmaxf(sum2 / fn - miu * miu, 1e-12f);

    // KDE: lane = bin, 4 waves split pixels, 4 exp chains
    const float binv  = -5.0f + 0.2f * (float)lane;
    const float coef2 = (-0.5f / (var * 0.04f)) * LOG2E_F;
    float a0 = 0.f, a1 = 0.f, a2 = 0.f, a3 = 0.f;
    for (int i = wave * 4; i < N4t0; i += 16) {
        float4 v = *(const float4*)&xs[i];
        float d0 = binv - v.x, d1 = binv - v.y, d2 = binv - v.z, d3 = binv - v.w;
        a0 += EXP2F(coef2 * d0 * d0);
        a1 += EXP2F(coef2 * d1 * d1);
        a2 += EXP2F(coef2 * d2 * d2);
        a3 += EXP2F(coef2 * d3 * d3);
    }
    // rare multi-tile path (n > TILE) — correctness for arbitrary inputs
    for (int t0 = TILE; t0 < n; t0 += TILE) {
        __syncthreads();
        int nt = n - t0; if (nt > TILE) nt = TILE;
        for (int i = tid; i < nt; i += 256) xs[i] = xrow[idx_g[st + t0 + i]];
        int N4t = (nt + 3) & ~3;
        if (tid < N4t - nt) xs[nt + tid] = 1e19f;
        __syncthreads();
        for (int i = wave * 4; i < N4t; i += 16) {
            float4 v = *(const float4*)&xs[i];
            float d0 = binv - v.x, d1 = binv - v.y, d2 = binv - v.z, d3 = binv - v.w;
            a0 += EXP2F(coef2 * d0 * d0);
            a1 += EXP2F(coef2 * d1 * d1);
            a2 += EXP2F(coef2 * d2 * d2);
            a3 += EXP2F(coef2 * d3 * d3);
        }
    }
    s_acc[wave][lane] = (a0 + a1) + (a2 + a3);
    __syncthreads();

    if (wave == 0) {
        float kde = s_acc[0][lane] + s_acc[1][lane] + s_acc[2][lane] + s_acc[3][lane];
        float vs  = var * 0.04f;
        float dt  = binv - miu;
        float tg  = EXP2F(((-0.5f / var) * LOG2E_F) * dt * dt);
        if (lane >= BINS) { kde = 0.f; tg = 0.f; }
        float sv = kde * rsqrtf(TWO_PI_F * vs);
        float tt = tg  * rsqrtf(TWO_PI_F * var);
        float ssum = sv, tsum = tt;
        #pragma unroll
        for (int off = 32; off; off >>= 1) {
            ssum += __shfl_xor(ssum, off, 64);
            tsum += __shfl_xor(tsum, off, 64);
        }
        float hist  = sv / fmaxf(ssum, 1e-12f);
        float tnorm = tt / tsum;
        float diff  = hist - tnorm;
        float ad    = fabsf(diff);
        float sl1   = (ad < 1.0f) ? 0.5f * diff * diff : (ad - 0.5f);
        if (lane >= BINS) sl1 = 0.f;
        #pragma unroll
        for (int off = 32; off; off >>= 1) sl1 += __shfl_xor(sl1, off, 64);
        if (lane == 0) partial[cm1 * NFEAT + f] = sl1;
    }
}

// ---- kernel 2: deterministic f64 reduction ----
__global__ __launch_bounds__(256)
void hist_final(const float* __restrict__ partial, const int* __restrict__ base_g,
                float* __restrict__ out) {
    const int tid = threadIdx.x, lane = tid & 63, wave = tid >> 6;
    __shared__ double sd[4];

    double s = 0.0;
    for (int i = tid; i < NFEAT * (NCLS - 1); i += 256) s += (double)partial[i];
    #pragma unroll
    for (int off = 32; off; off >>= 1) s += __shfl_xor(s, off, 64);
    if (lane == 0) sd[wave] = s;
    __syncthreads();
    if (tid == 0) {
        double tot = sd[0] + sd[1] + sd[2] + sd[3];
        int active = 0;
        for (int c = 1; c < NCLS; ++c) active += (base_g[c + 1] - base_g[c] > 0) ? 1 : 0;
        double loss = tot / (double)(NFEAT * BINS) / ((double)active + 1e-12);
        out[0] = (float)loss;
    }
}

extern "C" void kernel_launch(void* const* d_in, const int* in_sizes, int n_in,
                              void* d_out, int out_size, void* d_ws, size_t ws_size,
                              hipStream_t stream) {
    const float* x   = (const float*)d_in[0];
    const int*   lab = (const int*)d_in[1];
    float* out       = (float*)d_out;
    float* partial   = (float*)d_ws;
    int*   base_g    = (int*)((char*)d_ws + 18944);
    int*   idx_g     = (int*)((char*)d_ws + 19072);

    hipLaunchKernelGGL(bucket_k, dim3(1), dim3(1024), 0, stream, lab, base_g, idx_g);
    hipLaunchKernelGGL(hist_main, dim3(NFEAT, NCLS - 1), dim3(256), 0, stream,
                       x, base_g, idx_g, partial);
    hipLaunchKernelGGL(hist_final, dim3(1), dim3(256), 0, stream, partial, base_g, out);
}